// Round 7
// baseline (324.802 us; speedup 1.0000x reference)
//
#include <hip/hip_runtime.h>

#define BATCH   8192
#define HIST    50
#define REPR    512
#define N_EMB   100000
#define NSLICE  4
#define SLICE_SZ ((N_EMB + NSLICE - 1) / NSLICE)   // 25000 rows = 51.2 MB
#define NBLK    1024                               // <= capacity (4 blk/CU)
#define ROWS_PB (BATCH / NBLK)                     // 8 rows per block
#define CH      8
#define SPIN_LIMIT (1u << 16)

typedef float v4f __attribute__((ext_vector_type(4)));

// Zero the per-phase barrier counters each launch (ws is poisoned once by
// the harness and never re-poisoned -> must re-init every call).
__global__ void init_counters_kernel(unsigned int* cnt) {
    if (threadIdx.x < NSLICE) cnt[threadIdx.x] = 0u;
}

// Soft-barrier slice-phased embedding-bag sum.
// All 1024 blocks are co-resident (launch_bounds caps VGPR so >=4 blk/CU).
// After each 51 MB table slice, blocks arrive at a bounded-spin barrier:
// chip-wide active footprint stays one slice at a time (<< 256 MB L3), so
// each unique table row is HBM-fetched once and its ~3.3 reuses hit L3.
// The barrier is PERFORMANCE-ONLY: accumulators are per-block registers, so
// a timed-out barrier only loses phasing, never correctness.
__global__ __launch_bounds__(256, 4) void embbag_phased_kernel(
    const int* __restrict__ target,      // [BATCH, HIST], -1 = sentinel
    const float* __restrict__ emb,       // [N_EMB, REPR]
    float* __restrict__ out,             // [BATCH, REPR]
    unsigned int* __restrict__ cnt)      // [NSLICE] barrier counters
{
    __shared__ int s_idx[ROWS_PB][NSLICE][HIST + 2];
    __shared__ int s_cnt[ROWS_PB][NSLICE];

    const int g    = threadIdx.x >> 7;   // group 0/1 (128 threads each)
    const int lane = threadIdx.x & 127;  // float4 slot
    const int base = blockIdx.x * ROWS_PB;

    // ---- stage 1: bucket all 8 rows' valid indices by table slice ----
    if (threadIdx.x < ROWS_PB * NSLICE)
        s_cnt[threadIdx.x >> 2][threadIdx.x & 3] = 0;   // NSLICE == 4
    __syncthreads();
    for (int t = threadIdx.x; t < ROWS_PB * HIST; t += 256) {
        const int r  = t / HIST;
        const int j  = t - r * HIST;
        const int ix = target[(base + r) * HIST + j];
        if (ix >= 0) {
            const int b   = ix / SLICE_SZ;
            const int pos = atomicAdd(&s_cnt[r][b], 1);
            s_idx[r][b][pos] = ix;
        }
    }
    __syncthreads();

    // ---- stage 2: gather, slice phase by slice phase ----
    const float* col = emb + (size_t)lane * 4;
    float4 acc[ROWS_PB / 2];
#pragma unroll
    for (int c = 0; c < ROWS_PB / 2; ++c)
        acc[c] = make_float4(0.f, 0.f, 0.f, 0.f);

    for (int p = 0; p < NSLICE; ++p) {
#pragma unroll
        for (int c = 0; c < ROWS_PB / 2; ++c) {
            const int r = c * 2 + g;
            const int n = s_cnt[r][p];
            for (int k0 = 0; k0 < n; k0 += CH) {
                int    idx[CH];
                float  w[CH];
                float4 v[CH];
#pragma unroll
                for (int k = 0; k < CH; ++k) {
                    const bool valid = (k0 + k) < n;
                    idx[k] = valid ? s_idx[r][p][k0 + k] : 0;
                    w[k]   = valid ? 1.0f : 0.0f;
                }
#pragma unroll
                for (int k = 0; k < CH; ++k) {
                    v[k] = *reinterpret_cast<const float4*>(col + (size_t)idx[k] * REPR);
                }
#pragma unroll
                for (int k = 0; k < CH; ++k) {
                    acc[c].x = fmaf(v[k].x, w[k], acc[c].x);
                    acc[c].y = fmaf(v[k].y, w[k], acc[c].y);
                    acc[c].z = fmaf(v[k].z, w[k], acc[c].z);
                    acc[c].w = fmaf(v[k].w, w[k], acc[c].w);
                }
            }
        }
        // ---- bounded soft grid barrier (performance-only) ----
        if (p < NSLICE - 1) {
            __syncthreads();
            if (threadIdx.x == 0) {
                __hip_atomic_fetch_add(&cnt[p], 1u, __ATOMIC_RELAXED,
                                       __HIP_MEMORY_SCOPE_AGENT);
                unsigned int spins = 0;
                while (__hip_atomic_load(&cnt[p], __ATOMIC_RELAXED,
                                         __HIP_MEMORY_SCOPE_AGENT) < NBLK &&
                       spins < SPIN_LIMIT) {
                    ++spins;
                    __builtin_amdgcn_s_sleep(2);
                }
            }
            __syncthreads();
        }
    }

    // ---- epilogue: one nontemporal store per owned row ----
#pragma unroll
    for (int c = 0; c < ROWS_PB / 2; ++c) {
        const int row = base + c * 2 + g;
        v4f av;
        av.x = acc[c].x; av.y = acc[c].y; av.z = acc[c].z; av.w = acc[c].w;
        v4f* o = reinterpret_cast<v4f*>(out + (size_t)row * REPR + (size_t)lane * 4);
        __builtin_nontemporal_store(av, o);
    }
}

extern "C" void kernel_launch(void* const* d_in, const int* in_sizes, int n_in,
                              void* d_out, int out_size, void* d_ws, size_t ws_size,
                              hipStream_t stream) {
    const int*    target = (const int*)d_in[0];
    const float*  emb    = (const float*)d_in[1];
    float*        out    = (float*)d_out;
    unsigned int* cnt    = (unsigned int*)d_ws;

    init_counters_kernel<<<1, 64, 0, stream>>>(cnt);
    embbag_phased_kernel<<<dim3(NBLK), dim3(256), 0, stream>>>(
        target, emb, out, cnt);
}

// Round 8
// 96.656 us; speedup vs baseline: 3.3604x; 3.3604x over previous
//
#include <hip/hip_runtime.h>

#define BATCH 8192
#define HIST  50
#define REPR  512

typedef float v4f __attribute__((ext_vector_type(4)));

// Embedding-bag sum (best variant: round-1 structure + nontemporal store).
// One batch row = 128 threads, each owning one float4 (16 B) of the 512-dim
// embedding -> each table-row gather is a fully-coalesced 2048 B access.
// 2 rows per 256-thread block, grid = 4096 blocks, 12 VGPR -> max occupancy.
// Demand traffic (674 MB reads + 17 MB writes) runs at the chip's measured
// delivered-BW ceiling (~7.1 TB/s); deeper MLP batching, LDS bucketing, and
// chip-wide slice phasing were all tried and are null or negative.
__global__ __launch_bounds__(256) void embbag_sum_kernel(
    const int* __restrict__ target,      // [BATCH, HIST], -1 = sentinel
    const float* __restrict__ emb,       // [N_EMB, REPR]
    float* __restrict__ out)             // [BATCH, REPR]
{
    const int row  = blockIdx.x * 2 + (threadIdx.x >> 7);
    const int lane = threadIdx.x & 127;

    const int* t = target + row * HIST;
    const float* col = emb + (size_t)lane * 4;

    float4 acc = make_float4(0.f, 0.f, 0.f, 0.f);

#pragma unroll 5
    for (int j = 0; j < HIST; ++j) {
        const int idx = t[j];  // wave-uniform broadcast load
        if (idx >= 0) {
            const float4 v =
                *reinterpret_cast<const float4*>(col + (size_t)idx * REPR);
            acc.x += v.x;
            acc.y += v.y;
            acc.z += v.z;
            acc.w += v.w;
        }
    }

    v4f av;
    av.x = acc.x; av.y = acc.y; av.z = acc.z; av.w = acc.w;
    v4f* o = reinterpret_cast<v4f*>(out + (size_t)row * REPR + (size_t)lane * 4);
    __builtin_nontemporal_store(av, o);
}

extern "C" void kernel_launch(void* const* d_in, const int* in_sizes, int n_in,
                              void* d_out, int out_size, void* d_ws, size_t ws_size,
                              hipStream_t stream) {
    const int*   target = (const int*)d_in[0];
    const float* emb    = (const float*)d_in[1];
    float*       out    = (float*)d_out;

    dim3 grid(BATCH / 2);
    dim3 block(256);
    embbag_sum_kernel<<<grid, block, 0, stream>>>(target, emb, out);
}